// Round 1
// baseline (5209.109 us; speedup 1.0000x reference)
//
#include <hip/hip_runtime.h>
#include <hip/hip_bf16.h>
#include <stdint.h>

#define BB 64
#define TT 512
#define DD 512
#define UU 1024
#define G4 4096     // 4*U
#define NWG 64
#define POLL_CAP 16384

typedef __bf16 bf16x8 __attribute__((ext_vector_type(8)));
typedef float f32x4 __attribute__((ext_vector_type(4)));
typedef unsigned short u16x8 __attribute__((ext_vector_type(8)));

__device__ __forceinline__ unsigned short f2bf(float f) {
  unsigned u = __builtin_bit_cast(unsigned, f);
  return (unsigned short)((u + 0x7FFFu + ((u >> 16) & 1u)) >> 16);  // RTN-even
}

// ---- x f32 -> bf16, same [B][T][D] layout, 8 elems/thread ----
__global__ void cvt_x_kernel(const float* __restrict__ x, unsigned short* __restrict__ xb, int n8) {
  int i = blockIdx.x * blockDim.x + threadIdx.x;
  if (i >= n8) return;
  const float4* p = reinterpret_cast<const float4*>(x) + (size_t)i * 2;
  float4 a = p[0], b = p[1];
  u16x8 o;
  o[0] = f2bf(a.x); o[1] = f2bf(a.y); o[2] = f2bf(a.z); o[3] = f2bf(a.w);
  o[4] = f2bf(b.x); o[5] = f2bf(b.y); o[6] = f2bf(b.z); o[7] = f2bf(b.w);
  reinterpret_cast<u16x8*>(xb)[i] = o;
}

__global__ void zero_kernel(unsigned int* __restrict__ p, int nwords) {
  for (int i = blockIdx.x * blockDim.x + threadIdx.x; i < nwords; i += gridDim.x * blockDim.x)
    p[i] = 0u;
}

// ---- persistent LSTM recurrence kernel ----
// 64 WGs x 256 threads. WG wg owns u in [wg*16, wg*16+16).
// Wave w K-splits: x-part k in [w*128, w*128+128), h-part k in [w*256, w*256+256).
// B-fragments (W,R slices) live in registers for the whole kernel.
__launch_bounds__(256, 1)
__global__ void lstm_persist(const float* __restrict__ W, const float* __restrict__ R,
                             const float* __restrict__ bias,
                             const unsigned short* __restrict__ xb,
                             unsigned short* __restrict__ hbuf,  // [2][64][1024] bf16
                             int* flags, float* __restrict__ out) {
  __shared__ f32x4 zone[4 * 4 * 4 * 64];  // [rb_phys][wsrc][cb][lane], 64 KB

  const int wg = blockIdx.x;
  const int tid = threadIdx.x;
  const int w = tid >> 6;        // wave 0..3
  const int lane = tid & 63;
  const int l15 = lane & 15;
  const int lk = lane >> 4;      // 0..3
  const int u0 = wg * 16;

  // ---- load B fragments (once). B-frag: B[k = k0 + lk*8 + j][col = gcol] ----
  bf16x8 Wf[4][4];   // [cb][s]  cb = gate, s = k-step within this wave's x range
  bf16x8 Rf[4][8];   // [cb][s]
  #pragma unroll
  for (int cb = 0; cb < 4; ++cb) {
    const int gcol = cb * 1024 + u0 + l15;
    #pragma unroll
    for (int s = 0; s < 4; ++s) {
      const int k0 = w * 128 + s * 32 + lk * 8;
      u16x8 tmp;
      #pragma unroll
      for (int j = 0; j < 8; ++j) tmp[j] = f2bf(W[(size_t)(k0 + j) * G4 + gcol]);
      Wf[cb][s] = __builtin_bit_cast(bf16x8, tmp);
    }
    #pragma unroll
    for (int s = 0; s < 8; ++s) {
      const int k0 = w * 256 + s * 32 + lk * 8;
      u16x8 tmp;
      #pragma unroll
      for (int j = 0; j < 8; ++j) tmp[j] = f2bf(R[(size_t)(k0 + j) * G4 + gcol]);
      Rf[cb][s] = __builtin_bit_cast(bf16x8, tmp);
    }
  }
  float bv[4];
  #pragma unroll
  for (int cb = 0; cb < 4; ++cb) bv[cb] = bias[cb * 1024 + u0 + l15];

  // rb_local relabel: rb_local 0 is this wave's own row-block (compile-time acc index)
  int rowp[4];
  #pragma unroll
  for (int rl = 0; rl < 4; ++rl) rowp[rl] = ((w + rl) & 3) * 16 + l15;

  float cst[4] = {0.f, 0.f, 0.f, 0.f};  // cell state for rows w*16 + lk*4 + r

  for (int t = 0; t < TT; ++t) {
    f32x4 acc[4][4];  // [rb_local][cb]
    #pragma unroll
    for (int rl = 0; rl < 4; ++rl) {
      #pragma unroll
      for (int cb = 0; cb < 4; ++cb) acc[rl][cb] = f32x4{0.f, 0.f, 0.f, 0.f};
    }

    // ---- x-part (no dependence on h; overlaps barrier wait) ----
    #pragma unroll
    for (int s = 0; s < 4; ++s) {
      bf16x8 Af[4];
      #pragma unroll
      for (int rl = 0; rl < 4; ++rl) {
        const unsigned short* ap =
            xb + (size_t)rowp[rl] * (TT * DD) + (size_t)t * DD + (w * 128 + s * 32 + lk * 8);
        Af[rl] = *reinterpret_cast<const bf16x8*>(ap);
      }
      #pragma unroll
      for (int cb = 0; cb < 4; ++cb) {
        #pragma unroll
        for (int rl = 0; rl < 4; ++rl)
          acc[rl][cb] = __builtin_amdgcn_mfma_f32_16x16x32_bf16(Af[rl], Wf[cb][s], acc[rl][cb], 0, 0, 0);
      }
    }

    // ---- wait until all WGs posted h for step t ----
    {
      int it = 0;
      while (__any(__hip_atomic_load(&flags[lane], __ATOMIC_RELAXED, __HIP_MEMORY_SCOPE_AGENT) < t) &&
             ++it < POLL_CAP) {
        __builtin_amdgcn_s_sleep(1);
      }
      __builtin_amdgcn_fence(__ATOMIC_ACQUIRE, "agent");
    }

    // ---- h-part ----
    const unsigned short* hin = hbuf + (size_t)(t & 1) * (BB * UU);
    #pragma unroll
    for (int s = 0; s < 8; ++s) {
      bf16x8 Af[4];
      #pragma unroll
      for (int rl = 0; rl < 4; ++rl) {
        const unsigned short* ap = hin + (size_t)rowp[rl] * UU + (w * 256 + s * 32 + lk * 8);
        Af[rl] = *reinterpret_cast<const bf16x8*>(ap);
      }
      #pragma unroll
      for (int cb = 0; cb < 4; ++cb) {
        #pragma unroll
        for (int rl = 0; rl < 4; ++rl)
          acc[rl][cb] = __builtin_amdgcn_mfma_f32_16x16x32_bf16(Af[rl], Rf[cb][s], acc[rl][cb], 0, 0, 0);
      }
    }

    // ---- exchange K-split partials (each wave keeps rb_local==0 = its own rows) ----
    #pragma unroll
    for (int rl = 1; rl < 4; ++rl) {
      const int rbp = (w + rl) & 3;
      #pragma unroll
      for (int cb = 0; cb < 4; ++cb)
        zone[((rbp * 4 + w) * 4 + cb) * 64 + lane] = acc[rl][cb];
    }
    __syncthreads();

    f32x4 z[4];
    #pragma unroll
    for (int cb = 0; cb < 4; ++cb) z[cb] = acc[0][cb];
    #pragma unroll
    for (int ws = 1; ws < 4; ++ws) {
      const int wsrc = (w + ws) & 3;
      #pragma unroll
      for (int cb = 0; cb < 4; ++cb)
        z[cb] += zone[((w * 4 + wsrc) * 4 + cb) * 64 + lane];
    }

    // ---- gates (lane-local: cb == gate index), c-state in registers ----
    unsigned short* hout = hbuf + (size_t)((t + 1) & 1) * (BB * UU);
    #pragma unroll
    for (int r = 0; r < 4; ++r) {
      const float zi = z[0][r] + bv[0];
      const float zf = z[1][r] + bv[1];
      const float zg = z[2][r] + bv[2];
      const float zo = z[3][r] + bv[3];
      const float ig = 1.f / (1.f + __expf(-zi));
      const float fg = 1.f / (1.f + __expf(-zf));
      const float gg = 1.f - 2.f / (1.f + __expf(2.f * zg));  // tanh, inf-safe
      const float og = 1.f / (1.f + __expf(-zo));
      const float c = fg * cst[r] + ig * gg;
      cst[r] = c;
      const float h = og * (1.f - 2.f / (1.f + __expf(2.f * c)));
      const int row = w * 16 + lk * 4 + r;
      hout[(size_t)row * UU + u0 + l15] = f2bf(h);
      if (t == TT - 1) out[(size_t)row * UU + u0 + l15] = h;
    }

    __syncthreads();  // drains all waves' vmcnt before the flag post
    if (tid == 0) {
      __builtin_amdgcn_fence(__ATOMIC_RELEASE, "agent");
      __hip_atomic_store(&flags[wg], t + 1, __ATOMIC_RELAXED, __HIP_MEMORY_SCOPE_AGENT);
    }
  }
}

extern "C" void kernel_launch(void* const* d_in, const int* in_sizes, int n_in,
                              void* d_out, int out_size, void* d_ws, size_t ws_size,
                              hipStream_t stream) {
  const float* x = (const float*)d_in[0];
  const float* W = (const float*)d_in[1];
  const float* R = (const float*)d_in[2];
  const float* b = (const float*)d_in[3];
  float* out = (float*)d_out;

  char* ws = (char*)d_ws;
  // ws layout: xb bf16 [B][T][D] (32 MB) | hbuf bf16 [2][64][1024] (256 KB) | flags (256 B)
  unsigned short* xb = (unsigned short*)ws;
  const size_t XB_BYTES = (size_t)BB * TT * DD * 2;            // 33554432
  unsigned short* hbuf = (unsigned short*)(ws + XB_BYTES);
  const size_t HB_BYTES = (size_t)2 * BB * UU * 2;             // 262144
  int* flags = (int*)(ws + XB_BYTES + HB_BYTES);

  // 1) convert x to bf16
  hipLaunchKernelGGL(cvt_x_kernel, dim3((BB * TT * DD / 8 + 255) / 256), dim3(256), 0, stream,
                     x, xb, BB * TT * DD / 8);
  // 2) zero h buffers + flags
  hipLaunchKernelGGL(zero_kernel, dim3(64), dim3(256), 0, stream,
                     (unsigned int*)(ws + XB_BYTES), (int)((HB_BYTES + 256) / 4));
  // 3) persistent recurrence
  hipLaunchKernelGGL(lstm_persist, dim3(NWG), dim3(256), 0, stream,
                     W, R, b, xb, hbuf, flags, out);
}

// Round 2
// 4016.343 us; speedup vs baseline: 1.2970x; 1.2970x over previous
//
#include <hip/hip_runtime.h>
#include <hip/hip_bf16.h>
#include <stdint.h>

#define BB 64
#define TT 512
#define DD 512
#define UU 1024
#define G4 4096     // 4*U
#define NWG 64
#define POLL_CAP 65536

typedef __bf16 bf16x8 __attribute__((ext_vector_type(8)));
typedef float f32x4 __attribute__((ext_vector_type(4)));
typedef unsigned short u16x8 __attribute__((ext_vector_type(8)));
typedef int i32x4 __attribute__((ext_vector_type(4)));
typedef int i32x2 __attribute__((ext_vector_type(2)));

__device__ __forceinline__ unsigned short f2bf(float f) {
  unsigned u = __builtin_bit_cast(unsigned, f);
  return (unsigned short)((u + 0x7FFFu + ((u >> 16) & 1u)) >> 16);  // RTN-even
}

// ---- x f32 -> bf16, same [B][T][D] layout, 8 elems/thread ----
__global__ void cvt_x_kernel(const float* __restrict__ x, unsigned short* __restrict__ xb, int n8) {
  int i = blockIdx.x * blockDim.x + threadIdx.x;
  if (i >= n8) return;
  const float4* p = reinterpret_cast<const float4*>(x) + (size_t)i * 2;
  float4 a = p[0], b = p[1];
  u16x8 o;
  o[0] = f2bf(a.x); o[1] = f2bf(a.y); o[2] = f2bf(a.z); o[3] = f2bf(a.w);
  o[4] = f2bf(b.x); o[5] = f2bf(b.y); o[6] = f2bf(b.z); o[7] = f2bf(b.w);
  reinterpret_cast<u16x8*>(xb)[i] = o;
}

// zero with write-through (sc0 sc1) so later sc1 loads see zeros at the
// coherence point (no reliance on packet-boundary L2 writeback).
__global__ void zero_kernel(unsigned int* __restrict__ p, int nwords) {
  for (int i = blockIdx.x * blockDim.x + threadIdx.x; i < nwords; i += gridDim.x * blockDim.x) {
    unsigned int z = 0u;
    const unsigned int* q = p + i;
    asm volatile("global_store_dword %0, %1, off sc0 sc1" :: "v"(q), "v"(z) : "memory");
  }
}

// ---- persistent LSTM recurrence kernel ----
// 64 WGs x 256 threads. WG wg owns u in [wg*16, wg*16+16).
// Wave w K-splits: x-part k in [w*128,+128), h-part k in [w*256,+256).
// W,R fragments live in registers for the whole kernel. h exchanged through
// a triple-buffered global bf16 buffer with sc0/sc1 (cache-bypass) accesses;
// per-wave flags; NO cache-wide fences -> x/W/R stay L2-cached.
__launch_bounds__(256, 1)
__global__ void lstm_persist(const float* __restrict__ W, const float* __restrict__ R,
                             const float* __restrict__ bias,
                             const unsigned short* __restrict__ xb,
                             unsigned short* __restrict__ hbuf,  // [3][64][1024] bf16
                             int* flags,                          // [64][4]
                             float* __restrict__ out) {
  __shared__ f32x4 zone[4 * 4 * 4 * 64];        // 16 KB: [rb_phys][wsrc][cb][lane]
  __shared__ unsigned short hstage[64][16];     // 2 KB: h staging for coalesced stores

  const int wg = blockIdx.x;
  const int tid = threadIdx.x;
  const int w = tid >> 6;        // wave 0..3
  const int lane = tid & 63;
  const int l15 = lane & 15;
  const int lk = lane >> 4;      // 0..3
  const int u0 = wg * 16;

  // ---- load B fragments (once). frag: B[k = k0 + lk*8 + j][col = gcol] ----
  bf16x8 Wf[4][4];   // [s][cb]
  bf16x8 Rf[8][4];   // [s][cb]
  #pragma unroll
  for (int cb = 0; cb < 4; ++cb) {
    const int gcol = cb * 1024 + u0 + l15;
    #pragma unroll
    for (int s = 0; s < 4; ++s) {
      const int k0 = w * 128 + s * 32 + lk * 8;
      u16x8 tmp;
      #pragma unroll
      for (int j = 0; j < 8; ++j) tmp[j] = f2bf(W[(size_t)(k0 + j) * G4 + gcol]);
      Wf[s][cb] = __builtin_bit_cast(bf16x8, tmp);
    }
    #pragma unroll
    for (int s = 0; s < 8; ++s) {
      const int k0 = w * 256 + s * 32 + lk * 8;
      u16x8 tmp;
      #pragma unroll
      for (int j = 0; j < 8; ++j) tmp[j] = f2bf(R[(size_t)(k0 + j) * G4 + gcol]);
      Rf[s][cb] = __builtin_bit_cast(bf16x8, tmp);
    }
  }
  float bv[4];
  #pragma unroll
  for (int cb = 0; cb < 4; ++cb) bv[cb] = bias[cb * 1024 + u0 + l15];

  // rb_local relabel: rb_local 0 is this wave's own row-block
  int rowp[4];
  #pragma unroll
  for (int rl = 0; rl < 4; ++rl) rowp[rl] = ((w + rl) & 3) * 16 + l15;

  float cst[4] = {0.f, 0.f, 0.f, 0.f};

  int bcur = 0;  // t % 3
  for (int t = 0; t < TT; ++t) {
    const int bnxt = (bcur == 2) ? 0 : bcur + 1;

    f32x4 acc[4][4];  // [rb_local][cb]
    #pragma unroll
    for (int rl = 0; rl < 4; ++rl)
      #pragma unroll
      for (int cb = 0; cb < 4; ++cb) acc[rl][cb] = f32x4{0.f, 0.f, 0.f, 0.f};

    // ---- x-part (plain cached loads; no dependence on h) ----
    #pragma unroll
    for (int s = 0; s < 4; ++s) {
      bf16x8 Af[4];
      #pragma unroll
      for (int rl = 0; rl < 4; ++rl) {
        const unsigned short* ap =
            xb + (size_t)rowp[rl] * (TT * DD) + (size_t)t * DD + (w * 128 + s * 32 + lk * 8);
        Af[rl] = *reinterpret_cast<const bf16x8*>(ap);
      }
      #pragma unroll
      for (int cb = 0; cb < 4; ++cb)
        #pragma unroll
        for (int rl = 0; rl < 4; ++rl)
          acc[rl][cb] = __builtin_amdgcn_mfma_f32_16x16x32_bf16(Af[rl], Wf[s][cb], acc[rl][cb], 0, 0, 0);
    }

    // ---- poll: wave w needs WGs [w*16, w*16+16) => flags[w*64 .. w*64+64) ----
    if (t > 0) {
      const int* fp = flags + w * 64 + lane;
      for (int it = 0; it < POLL_CAP; ++it) {
        int f;
        asm volatile("global_load_dword %0, %1, off sc0 sc1\n\t"
                     "s_waitcnt vmcnt(0)"
                     : "=v"(f) : "v"(fp) : "memory");
        if (!__any(f < t)) break;
      }
    }

    // ---- h-part: cache-bypass loads, 2-group pipeline with counted vmcnt ----
    {
      const unsigned short* hin = hbuf + (size_t)bcur * (BB * UU);
      i32x4 Aa[4], Ab[4];

      auto hload4 = [&](i32x4* A, int s) {
        const int kb = w * 256 + s * 32 + lk * 8;
        const unsigned short* p0 = hin + (size_t)rowp[0] * UU + kb;
        const unsigned short* p1 = hin + (size_t)rowp[1] * UU + kb;
        const unsigned short* p2 = hin + (size_t)rowp[2] * UU + kb;
        const unsigned short* p3 = hin + (size_t)rowp[3] * UU + kb;
        asm volatile(
            "global_load_dwordx4 %0, %4, off sc0 sc1\n\t"
            "global_load_dwordx4 %1, %5, off sc0 sc1\n\t"
            "global_load_dwordx4 %2, %6, off sc0 sc1\n\t"
            "global_load_dwordx4 %3, %7, off sc0 sc1"
            : "=&v"(A[0]), "=&v"(A[1]), "=&v"(A[2]), "=&v"(A[3])
            : "v"(p0), "v"(p1), "v"(p2), "v"(p3)
            : "memory");
      };

      hload4(Aa, 0);
      hload4(Ab, 1);
      #pragma unroll
      for (int sp = 0; sp < 4; ++sp) {
        asm volatile("s_waitcnt vmcnt(4)" ::: "memory");
        __builtin_amdgcn_sched_barrier(0);
        #pragma unroll
        for (int cb = 0; cb < 4; ++cb)
          #pragma unroll
          for (int rl = 0; rl < 4; ++rl)
            acc[rl][cb] = __builtin_amdgcn_mfma_f32_16x16x32_bf16(
                __builtin_bit_cast(bf16x8, Aa[rl]), Rf[2 * sp][cb], acc[rl][cb], 0, 0, 0);
        if (sp < 3) hload4(Aa, 2 * sp + 2);

        if (sp < 3) { asm volatile("s_waitcnt vmcnt(4)" ::: "memory"); }
        else        { asm volatile("s_waitcnt vmcnt(0)" ::: "memory"); }
        __builtin_amdgcn_sched_barrier(0);
        #pragma unroll
        for (int cb = 0; cb < 4; ++cb)
          #pragma unroll
          for (int rl = 0; rl < 4; ++rl)
            acc[rl][cb] = __builtin_amdgcn_mfma_f32_16x16x32_bf16(
                __builtin_bit_cast(bf16x8, Ab[rl]), Rf[2 * sp + 1][cb], acc[rl][cb], 0, 0, 0);
        if (sp < 3) hload4(Ab, 2 * sp + 3);
      }
    }

    // ---- exchange K-split partials through LDS ----
    #pragma unroll
    for (int rl = 1; rl < 4; ++rl) {
      const int rbp = (w + rl) & 3;
      #pragma unroll
      for (int cb = 0; cb < 4; ++cb)
        zone[((rbp * 4 + w) * 4 + cb) * 64 + lane] = acc[rl][cb];
    }
    __syncthreads();

    f32x4 z[4];
    #pragma unroll
    for (int cb = 0; cb < 4; ++cb) z[cb] = acc[0][cb];
    #pragma unroll
    for (int ws = 1; ws < 4; ++ws) {
      const int wsrc = (w + ws) & 3;
      #pragma unroll
      for (int cb = 0; cb < 4; ++cb)
        z[cb] += zone[((w * 4 + wsrc) * 4 + cb) * 64 + lane];
    }

    // ---- gates; stage h into LDS; out on last step ----
    #pragma unroll
    for (int r = 0; r < 4; ++r) {
      const float zi = z[0][r] + bv[0];
      const float zf = z[1][r] + bv[1];
      const float zg = z[2][r] + bv[2];
      const float zo = z[3][r] + bv[3];
      const float ig = 1.f / (1.f + __expf(-zi));
      const float fg = 1.f / (1.f + __expf(-zf));
      const float gg = 1.f - 2.f / (1.f + __expf(2.f * zg));  // tanh, inf-safe
      const float og = 1.f / (1.f + __expf(-zo));
      const float c = fg * cst[r] + ig * gg;
      cst[r] = c;
      const float h = og * (1.f - 2.f / (1.f + __expf(2.f * c)));
      const int row = w * 16 + lk * 4 + r;
      hstage[row][l15] = f2bf(h);
      if (t == TT - 1) out[(size_t)row * UU + u0 + l15] = h;
    }
    __syncthreads();

    // ---- coalesced write-through h store: 8 B per lane ----
    {
      unsigned short* hnxt = hbuf + (size_t)bnxt * (BB * UU);
      const int srow = tid >> 2;
      const int scol = (tid & 3) << 2;
      i32x2 hv = *reinterpret_cast<const i32x2*>(&hstage[srow][scol]);
      unsigned short* gp = hnxt + (size_t)srow * UU + u0 + scol;
      asm volatile("global_store_dwordx2 %0, %1, off sc0 sc1" :: "v"(gp), "v"(hv) : "memory");
    }
    asm volatile("s_waitcnt vmcnt(0)" ::: "memory");
    if (lane == 0) {
      const int fv = t + 1;
      const int* fp = flags + wg * 4 + w;
      asm volatile("global_store_dword %0, %1, off sc0 sc1" :: "v"(fp), "v"(fv) : "memory");
    }
    bcur = bnxt;
  }
}

extern "C" void kernel_launch(void* const* d_in, const int* in_sizes, int n_in,
                              void* d_out, int out_size, void* d_ws, size_t ws_size,
                              hipStream_t stream) {
  const float* x = (const float*)d_in[0];
  const float* W = (const float*)d_in[1];
  const float* R = (const float*)d_in[2];
  const float* b = (const float*)d_in[3];
  float* out = (float*)d_out;

  char* ws = (char*)d_ws;
  // ws layout: xb bf16 [B][T][D] (32 MB) | hbuf bf16 [3][64][1024] | flags [64][4]
  unsigned short* xb = (unsigned short*)ws;
  const size_t XB_BYTES = (size_t)BB * TT * DD * 2;        // 33554432
  unsigned short* hbuf = (unsigned short*)(ws + XB_BYTES);
  const size_t HB_BYTES = (size_t)3 * BB * UU * 2;         // 393216
  int* flags = (int*)(ws + XB_BYTES + HB_BYTES);
  const size_t FL_BYTES = NWG * 4 * sizeof(int);           // 1024

  // 1) convert x to bf16
  hipLaunchKernelGGL(cvt_x_kernel, dim3((BB * TT * DD / 8 + 255) / 256), dim3(256), 0, stream,
                     x, xb, BB * TT * DD / 8);
  // 2) zero h buffers + flags (write-through)
  hipLaunchKernelGGL(zero_kernel, dim3(64), dim3(256), 0, stream,
                     (unsigned int*)(ws + XB_BYTES), (int)((HB_BYTES + FL_BYTES) / 4));
  // 3) persistent recurrence
  hipLaunchKernelGGL(lstm_persist, dim3(NWG), dim3(256), 0, stream,
                     W, R, b, xb, hbuf, flags, out);
}

// Round 7
// 3937.278 us; speedup vs baseline: 1.3230x; 1.0201x over previous
//
#include <hip/hip_runtime.h>
#include <hip/hip_bf16.h>
#include <stdint.h>

#define BB 64
#define TT 512
#define DD 512
#define UU 1024
#define G4 4096
#define RETRY_CAP 16384

typedef __bf16 bf16x8 __attribute__((ext_vector_type(8)));
typedef float f32x4 __attribute__((ext_vector_type(4)));
typedef unsigned short u16x8 __attribute__((ext_vector_type(8)));
typedef int i32x4 __attribute__((ext_vector_type(4)));
typedef unsigned int u32;

__device__ __forceinline__ unsigned short f2bf(float f) {
  unsigned u = __builtin_bit_cast(unsigned, f);
  return (unsigned short)((u + 0x7FFFu + ((u >> 16) & 1u)) >> 16);  // RTN-even
}

// ---- x f32 -> bf16, same [B][T][D] layout, 8 elems/thread ----
__global__ void cvt_x_kernel(const float* __restrict__ x, unsigned short* __restrict__ xb, int n8) {
  int i = blockIdx.x * blockDim.x + threadIdx.x;
  if (i >= n8) return;
  const float4* p = reinterpret_cast<const float4*>(x) + (size_t)i * 2;
  float4 a = p[0], b = p[1];
  u16x8 o;
  o[0] = f2bf(a.x); o[1] = f2bf(a.y); o[2] = f2bf(a.z); o[3] = f2bf(a.w);
  o[4] = f2bf(b.x); o[5] = f2bf(b.y); o[6] = f2bf(b.z); o[7] = f2bf(b.w);
  reinterpret_cast<u16x8*>(xb)[i] = o;
}

// zero hbuf with write-through so sc0sc1 readers see 0 tags (R2-proven access type)
__global__ void zero_kernel(u32* __restrict__ p, int nwords) {
  for (int i = blockIdx.x * blockDim.x + threadIdx.x; i < nwords; i += gridDim.x * blockDim.x) {
    u32 z = 0u;
    const u32* q = p + i;
    asm volatile("global_store_dword %0, %1, off sc0 sc1" :: "v"(q), "v"(z) : "memory");
  }
}

// ---- persistent LSTM recurrence, flag-free self-validating h exchange ----
// 128 WGs x 512 thr (8 waves). bgrp=bid>>6 owns batch rows [bgrp*32,+32);
// m=bid&63 owns u [m*16,+16). Two INDEPENDENT 64-WG cliques (pure blockIdx
// partition -- no dispatch/XCD assumptions; 128 WGs <= 256 CUs so always
// co-resident). Wave w k-split: x [w*64,+64), h [w*128,+128).
// Weights in registers (~220 VGPR, no spill).
// h stored as u32 (bf16<<16 | step_tag): per-dword atomic self-validation,
// so NO flags, NO store drain; consumer speculates + validates + retries.
__launch_bounds__(512, 1)
__global__ void lstm_persist(const float* __restrict__ W, const float* __restrict__ R,
                             const float* __restrict__ bias,
                             const unsigned short* __restrict__ xb,
                             u32* __restrict__ hbuf,   // [2 bgrp][2 buf][32][1024] u32
                             float* __restrict__ out) {
  __shared__ float zone[2 * 8 * 4 * 4 * 64];  // [rb][src][g][c][lane] f32, 64 KB

  const int bid = blockIdx.x;
  const int bgrp = bid >> 6;
  const int m = bid & 63;
  const int tid = threadIdx.x;
  const int w = tid >> 6;           // 0..7
  const int lane = tid & 63, l15 = lane & 15, lk = lane >> 4;
  const int rb = w & 1, rsel = w >> 1;  // gate ownership: row rb*16+lk*4+rsel
  const int u0 = m * 16;

  // ---- persistent weight fragments. B-frag: B[k0 + lk*8 + j][gcol] ----
  bf16x8 Wf[2][4];   // x: s=0..1, k0 = w*64 + s*32
  bf16x8 Rf[4][4];   // h: s=0..3, k0 = w*128 + s*32
  #pragma unroll
  for (int g = 0; g < 4; ++g) {
    const int gcol = g * 1024 + u0 + l15;
    #pragma unroll
    for (int s = 0; s < 2; ++s) {
      const int k0 = w * 64 + s * 32 + lk * 8;
      u16x8 tmp;
      #pragma unroll
      for (int j = 0; j < 8; ++j) tmp[j] = f2bf(W[(size_t)(k0 + j) * G4 + gcol]);
      Wf[s][g] = __builtin_bit_cast(bf16x8, tmp);
    }
    #pragma unroll
    for (int s = 0; s < 4; ++s) {
      const int k0 = w * 128 + s * 32 + lk * 8;
      u16x8 tmp;
      #pragma unroll
      for (int j = 0; j < 8; ++j) tmp[j] = f2bf(R[(size_t)(k0 + j) * G4 + gcol]);
      Rf[s][g] = __builtin_bit_cast(bf16x8, tmp);
    }
  }
  float bv[4];
  #pragma unroll
  for (int g = 0; g < 4; ++g) bv[g] = bias[g * 1024 + u0 + l15];

  float cst = 0.f;  // cell state for (row rb*16+lk*4+rsel, col u0+l15)

  // ---- pointers ----
  const unsigned short* xr0 = xb + (size_t)(bgrp * 32 + 0 + l15) * (TT * DD) + w * 64 + lk * 8;
  const unsigned short* xr1 = xb + (size_t)(bgrp * 32 + 16 + l15) * (TT * DD) + w * 64 + lk * 8;
  u32* hbg = hbuf + (size_t)bgrp * 2 * 32 * UU;
  // read bases per (parity, rl). A-frag lane (l15,lk) needs k = s*32 + lk*8 + [0..8)
  const u32* hrA0 = hbg + (size_t)(0 + l15) * UU + w * 128 + lk * 8;   // buf0, rl0
  const u32* hrA1 = hbg + (size_t)(16 + l15) * UU + w * 128 + lk * 8;  // buf0, rl1
  const u32* hrB0 = hrA0 + 32 * UU;                                    // buf1, rl0
  const u32* hrB1 = hrA1 + 32 * UU;                                    // buf1, rl1
  // store base per parity (this lane's single h word)
  u32* hsA = hbg + (size_t)(rb * 16 + lk * 4 + rsel) * UU + u0 + l15;  // buf0
  u32* hsB = hsA + 32 * UU;                                            // buf1

  // drain weight-load traffic before entering counted-vmcnt region
  asm volatile("s_waitcnt vmcnt(0)" ::: "memory");
  __builtin_amdgcn_sched_barrier(0);

  i32x4 H0[2][2], H1[2][2];  // [rl][q] for s-parity 0 / 1

#define HISSUE(Harr, S)                                                          \
  {                                                                              \
    const u32* p0 = b0 + (S) * 32;                                               \
    const u32* p1 = b1 + (S) * 32;                                               \
    asm volatile(                                                                \
        "global_load_dwordx4 %0, %4, off sc0 sc1\n\t"                            \
        "global_load_dwordx4 %1, %4, off offset:16 sc0 sc1\n\t"                  \
        "global_load_dwordx4 %2, %5, off sc0 sc1\n\t"                            \
        "global_load_dwordx4 %3, %5, off offset:16 sc0 sc1"                      \
        : "=&v"(Harr[0][0]), "=&v"(Harr[0][1]), "=&v"(Harr[1][0]), "=&v"(Harr[1][1]) \
        : "v"(p0), "v"(p1)                                                       \
        : "memory");                                                             \
  }

#define VBAD(Harr, badv)                                                         \
  {                                                                              \
    badv = 0;                                                                    \
    _Pragma("unroll") for (int rl = 0; rl < 2; ++rl)                             \
        _Pragma("unroll") for (int q = 0; q < 2; ++q)                            \
            _Pragma("unroll") for (int d = 0; d < 4; ++d)                        \
                badv |= (Harr[rl][q][d] ^ t) & 0xFFFF;                           \
  }

#define VSTEP(Harr, S, VC)                                                       \
  {                                                                              \
    asm volatile("s_waitcnt vmcnt(" #VC ")" ::: "memory");                       \
    __builtin_amdgcn_sched_barrier(0);                                           \
    int bad;                                                                     \
    VBAD(Harr, bad);                                                             \
    int rtry = 0;                                                                \
    while (__any(bad != 0) && ++rtry < RETRY_CAP) {                              \
      HISSUE(Harr, S);                                                           \
      asm volatile("s_waitcnt vmcnt(0)" ::: "memory");                           \
      __builtin_amdgcn_sched_barrier(0);                                         \
      VBAD(Harr, bad);                                                           \
    }                                                                            \
    _Pragma("unroll") for (int rl = 0; rl < 2; ++rl) {                           \
      i32x4 fr;                                                                  \
      fr[0] = __builtin_amdgcn_perm(Harr[rl][0][1], Harr[rl][0][0], 0x07060302); \
      fr[1] = __builtin_amdgcn_perm(Harr[rl][0][3], Harr[rl][0][2], 0x07060302); \
      fr[2] = __builtin_amdgcn_perm(Harr[rl][1][1], Harr[rl][1][0], 0x07060302); \
      fr[3] = __builtin_amdgcn_perm(Harr[rl][1][3], Harr[rl][1][2], 0x07060302); \
      _Pragma("unroll") for (int g = 0; g < 4; ++g)                              \
          acc[rl][g] = __builtin_amdgcn_mfma_f32_16x16x32_bf16(                  \
              __builtin_bit_cast(bf16x8, fr), Rf[S][g], acc[rl][g], 0, 0, 0);    \
    }                                                                            \
  }

  #pragma unroll 1
  for (int t = 0; t < TT; ++t) {
    const int zb = t & 1;
    f32x4 acc[2][4];
    #pragma unroll
    for (int rl = 0; rl < 2; ++rl)
      #pragma unroll
      for (int g = 0; g < 4; ++g) acc[rl][g] = f32x4{0.f, 0.f, 0.f, 0.f};

    // issue x loads (cached)
    i32x4 Ax[2][2];  // [rl][s]
    asm volatile(
        "global_load_dwordx4 %0, %4, off\n\t"
        "global_load_dwordx4 %1, %4, off offset:64\n\t"
        "global_load_dwordx4 %2, %5, off\n\t"
        "global_load_dwordx4 %3, %5, off offset:64"
        : "=&v"(Ax[0][0]), "=&v"(Ax[0][1]), "=&v"(Ax[1][0]), "=&v"(Ax[1][1])
        : "v"(xr0), "v"(xr1));
    xr0 += DD; xr1 += DD;

    const u32* b0 = zb ? hrB0 : hrA0;
    const u32* b1 = zb ? hrB1 : hrA1;

    if (t > 0) {
      // speculative h loads for s=0,1; flight overlaps x-MFMA
      HISSUE(H0, 0);
      HISSUE(H1, 1);
      asm volatile("s_waitcnt vmcnt(8)" ::: "memory");  // x done (drains prev h-store too)
      __builtin_amdgcn_sched_barrier(0);
    } else {
      asm volatile("s_waitcnt vmcnt(0)" ::: "memory");
      __builtin_amdgcn_sched_barrier(0);
    }

    // x-part MFMA
    #pragma unroll
    for (int s = 0; s < 2; ++s)
      #pragma unroll
      for (int rl = 0; rl < 2; ++rl)
        #pragma unroll
        for (int g = 0; g < 4; ++g)
          acc[rl][g] = __builtin_amdgcn_mfma_f32_16x16x32_bf16(
              __builtin_bit_cast(bf16x8, Ax[rl][s]), Wf[s][g], acc[rl][g], 0, 0, 0);

    if (t > 0) {
      VSTEP(H0, 0, 4); HISSUE(H0, 2);
      VSTEP(H1, 1, 4); HISSUE(H1, 3);
      VSTEP(H0, 2, 4);
      VSTEP(H1, 3, 0);
    }

    // ---- k-split exchange: zone[rb][src][g][c][lane], conflict-free f32 ----
    __syncthreads();  // WAR: previous step's zone reads complete
    #pragma unroll
    for (int rl = 0; rl < 2; ++rl)
      #pragma unroll
      for (int g = 0; g < 4; ++g)
        #pragma unroll
        for (int c = 0; c < 4; ++c)
          zone[((((rl * 8 + w) * 4 + g) * 4 + c) << 6) + lane] = acc[rl][g][c];
    __syncthreads();

    // ---- gates: this wave owns (row rb*16+lk*4+rsel, u u0+l15) ----
    float z[4];
    #pragma unroll
    for (int g = 0; g < 4; ++g) {
      float s = bv[g];
      #pragma unroll
      for (int src = 0; src < 8; ++src)
        s += zone[((((rb * 8 + src) * 4 + g) * 4 + rsel) << 6) + lane];
      z[g] = s;
    }
    const float ig = 1.f / (1.f + __expf(-z[0]));
    const float fg = 1.f / (1.f + __expf(-z[1]));
    const float gg = 1.f - 2.f / (1.f + __expf(2.f * z[2]));  // tanh, inf-safe
    const float og = 1.f / (1.f + __expf(-z[3]));
    const float c = fg * cst + ig * gg;
    cst = c;
    const float h = og * (1.f - 2.f / (1.f + __expf(2.f * c)));

    if (t < TT - 1) {
      const u32 hw = ((u32)f2bf(h) << 16) | (u32)(t + 1);  // tag for consumers at t+1
      u32* hs = zb ? hsA : hsB;                            // store into buf (t+1)&1
      asm volatile("global_store_dword %0, %1, off sc0 sc1" :: "v"(hs), "v"(hw) : "memory");
      // fire-and-forget: no drain, no flag
    } else {
      out[(size_t)(bgrp * 32 + rb * 16 + lk * 4 + rsel) * UU + u0 + l15] = h;
    }
  }
#undef HISSUE
#undef VBAD
#undef VSTEP
}

extern "C" void kernel_launch(void* const* d_in, const int* in_sizes, int n_in,
                              void* d_out, int out_size, void* d_ws, size_t ws_size,
                              hipStream_t stream) {
  const float* x = (const float*)d_in[0];
  const float* W = (const float*)d_in[1];
  const float* R = (const float*)d_in[2];
  const float* b = (const float*)d_in[3];
  float* out = (float*)d_out;

  char* ws = (char*)d_ws;
  unsigned short* xb = (unsigned short*)ws;                 // 32 MB
  const size_t XB_BYTES = (size_t)BB * TT * DD * 2;
  u32* hbuf = (u32*)(ws + XB_BYTES);                        // 2*2*32*1024*4 = 512 KB
  const int HB_WORDS = 2 * 2 * 32 * UU;

  hipLaunchKernelGGL(cvt_x_kernel, dim3((BB * TT * DD / 8 + 255) / 256), dim3(256), 0, stream,
                     x, xb, BB * TT * DD / 8);
  hipLaunchKernelGGL(zero_kernel, dim3(128), dim3(256), 0, stream, hbuf, HB_WORDS);
  hipLaunchKernelGGL(lstm_persist, dim3(128), dim3(512), 0, stream,
                     W, R, b, xb, hbuf, out);
}